// Round 2
// baseline (310.211 us; speedup 1.0000x reference)
//
#include <hip/hip_runtime.h>
#include <stdint.h>

#define N_Q   16384
#define N_CLS 1024
#define DIM_H 2048

typedef __bf16 bf16x8 __attribute__((ext_vector_type(8)));
typedef float  f32x4  __attribute__((ext_vector_type(4)));

__device__ __forceinline__ uint32_t f2bf(float f) {
    uint32_t u = __float_as_uint(f);
    u += 0x7fff + ((u >> 16) & 1);   // RNE
    return u >> 16;
}
// pack two fp32 -> two bf16 (round-to-nearest ties-away): 2 adds + 1 merge
__device__ __forceinline__ uint32_t pk2(float a, float b) {
    uint32_t ua = __float_as_uint(a) + 0x8000u;
    uint32_t ub = __float_as_uint(b) + 0x8000u;
    return (ua >> 16) | (ub & 0xFFFF0000u);
}

// direct-to-LDS 16B staging; HW dest = wave-uniform base + lane*16
__device__ __forceinline__ void load_lds16(const __bf16* g, __bf16* l) {
    __builtin_amdgcn_global_load_lds(
        (const __attribute__((address_space(1))) uint32_t*)g,
        (__attribute__((address_space(3))) uint32_t*)l, 16, 0, 0);
}

// prepass: cls_bf16[c*H+h] = bf16(cls_f32[c*H+h] * M_f32[h])  (12 MB stream)
__global__ void scale_cls_kernel(const float* __restrict__ cls,
                                 const float* __restrict__ M,
                                 uint16_t* __restrict__ o) {
    size_t e = ((size_t)blockIdx.x * 256 + threadIdx.x) * 4;
    float4 c = *(const float4*)(cls + e);
    float4 m = *(const float4*)(M + (e & (DIM_H - 1)));
    uint32_t lo = f2bf(c.x * m.x) | (f2bf(c.y * m.y) << 16);
    uint32_t hi = f2bf(c.z * m.z) | (f2bf(c.w * m.w) << 16);
    *(uint2*)(o + e) = make_uint2(lo, hi);
}

// 128x128 tile, BK=64, 4 waves, 4x4 mfma_f32_16x16x32_bf16 per wave.
// A (queries) read as fp32 DIRECTLY from global: reg-staged + converted to
// bf16 in-kernel (kills the 192 MB cvt_q prepass). Next k-tile's A global
// loads are issued right after the first barrier so HBM latency hides under
// the MFMA phase (T14 split). B staged via async global_load_lds (bf16,
// pre-scaled by M in the prepass).
// LDS XOR-8 swizzle (unchanged): chunk at (row r, pos p) holds k-chunk p^(r&7).
// Block mapping: xcd=b&7 owns row-panels 16*xcd..16*xcd+15 across all 8 cols.
__global__ __launch_bounds__(256)
void gemm_fused_kernel(const float* __restrict__ Qf,     // (N,H) fp32
                       const uint16_t* __restrict__ Bp,  // (C,H) bf16 pre-scaled
                       float* __restrict__ Out) {        // (N,C) fp32
    __shared__ __align__(16) __bf16 As[128 * 64];
    __shared__ __align__(16) __bf16 Bs[128 * 64];

    const int tid  = threadIdx.x;
    const int lane = tid & 63;
    const int wave = tid >> 6;

    const int b    = blockIdx.x;            // 0..1023
    const int xcd  = b & 7;
    const int t    = b >> 3;                // 0..127
    const int row0 = (xcd * 16 + (t >> 3)) * 128;   // query rows
    const int col0 = (t & 7) * 128;                 // class cols

    const int wm   = (wave >> 1) * 64;
    const int wn   = (wave & 1) * 64;
    const int frow = lane & 15;
    const int fq   = lane >> 4;

    const __bf16* B = (const __bf16*)Bp;

    // per-lane A chunk geometry (constant over k0):
    // LDS chunk c = (i*4+wave)*64 + lane; tile row r = c>>3; global k-chunk
    // g = (c&7)^(r&7)  -> LDS holds the same swizzled layout as before.
    int cidx[4], arow[4], agk[4];
#pragma unroll
    for (int i = 0; i < 4; ++i) {
        const int c = (i * 4 + wave) * 64 + lane;
        cidx[i] = c;
        arow[i] = c >> 3;
        agk[i]  = (c & 7) ^ ((c >> 3) & 7);
    }

    f32x4 acc[4][4] = {};
    float4 ra[4][2];                // in-flight A fp32 (4 chunks x 8 floats)

    // prologue: load A regs for k0 = 0
#pragma unroll
    for (int i = 0; i < 4; ++i) {
        const float* p = Qf + (size_t)(row0 + arow[i]) * DIM_H + agk[i] * 8;
        ra[i][0] = *(const float4*)p;
        ra[i][1] = *(const float4*)(p + 4);
    }

    for (int k0 = 0; k0 < DIM_H; k0 += 64) {
        // ---- convert in-flight A to bf16, ds_write to swizzled chunks ----
#pragma unroll
        for (int i = 0; i < 4; ++i) {
            uint4 w = make_uint4(pk2(ra[i][0].x, ra[i][0].y),
                                 pk2(ra[i][0].z, ra[i][0].w),
                                 pk2(ra[i][1].x, ra[i][1].y),
                                 pk2(ra[i][1].z, ra[i][1].w));
            *(uint4*)&As[cidx[i] * 8] = w;   // lane-contiguous 16B: conflict-free
        }
        // ---- stage 16KB B via async global_load_lds (unchanged) ----
#pragma unroll
        for (int i = 0; i < 4; ++i) {
            const int chunkbase = (i * 4 + wave) * 64;   // wave-uniform
            const int c = chunkbase + lane;
            const int r = c >> 3;
            const int g = (c & 7) ^ (r & 7);
            load_lds16(B + (size_t)(col0 + r) * DIM_H + k0 + g * 8,
                       &Bs[chunkbase * 8]);
        }
        __syncthreads();

        // ---- issue next k-tile's A loads; they complete under the MFMAs ----
        if (k0 + 64 < DIM_H) {
#pragma unroll
            for (int i = 0; i < 4; ++i) {
                const float* p = Qf + (size_t)(row0 + arow[i]) * DIM_H
                               + (k0 + 64) + agk[i] * 8;
                ra[i][0] = *(const float4*)p;
                ra[i][1] = *(const float4*)(p + 4);
            }
        }

        // ---- compute: 2 k-steps x 16 MFMA, swizzled fragment reads ----
#pragma unroll
        for (int ks = 0; ks < 2; ++ks) {
            bf16x8 af[4], bfr[4];
#pragma unroll
            for (int tt = 0; tt < 4; ++tt) {
                const int ra2 = wm + tt * 16 + frow;
                const int pa  = ((ks * 4 + fq) ^ (ra2 & 7)) * 8;
                af[tt] = *(const bf16x8*)&As[ra2 * 64 + pa];
                const int rb = wn + tt * 16 + frow;
                const int pb = ((ks * 4 + fq) ^ (rb & 7)) * 8;
                bfr[tt] = *(const bf16x8*)&Bs[rb * 64 + pb];
            }
#pragma unroll
            for (int i = 0; i < 4; ++i)
#pragma unroll
                for (int j = 0; j < 4; ++j)
                    acc[i][j] = __builtin_amdgcn_mfma_f32_16x16x32_bf16(
                        af[i], bfr[j], acc[i][j], 0, 0, 0);
        }
        __syncthreads();
    }

    // ---- epilogue: C/D layout col=lane&15, row=(lane>>4)*4+reg; fp32 out ----
#pragma unroll
    for (int i = 0; i < 4; ++i) {
#pragma unroll
        for (int j = 0; j < 4; ++j) {
            const int row = row0 + wm + i * 16 + fq * 4;
            const int col = col0 + wn + j * 16 + frow;
#pragma unroll
            for (int r = 0; r < 4; ++r)
                Out[(size_t)(row + r) * N_CLS + col] = acc[i][j][r];
        }
    }
}

// correctness fallback (fp32 end-to-end) if workspace is too small
__global__ void naive_kernel(const float* __restrict__ Q,
                             const float* __restrict__ C,
                             const float* __restrict__ M,
                             float* __restrict__ Out) {
    size_t idx = (size_t)blockIdx.x * 256 + threadIdx.x;
    int n = (int)(idx >> 10), c = (int)(idx & (N_CLS - 1));
    float s = 0.f;
    for (int h = 0; h < DIM_H; ++h)
        s += Q[(size_t)n * DIM_H + h] * C[(size_t)c * DIM_H + h] * M[h];
    Out[idx] = s;
}

extern "C" void kernel_launch(void* const* d_in, const int* in_sizes, int n_in,
                              void* d_out, int out_size, void* d_ws, size_t ws_size,
                              hipStream_t stream) {
    const float* cls = (const float*)d_in[0];   // (C,H)  = 2,097,152
    const float* q   = (const float*)d_in[1];   // (N,H)  = 33,554,432
    const float* M   = (const float*)d_in[2];   // (H,1)  = 2,048
    for (int i = 0; i < n_in; ++i) {
        if      (in_sizes[i] == N_CLS * DIM_H) cls = (const float*)d_in[i];
        else if (in_sizes[i] == N_Q * DIM_H)   q   = (const float*)d_in[i];
        else if (in_sizes[i] == DIM_H)         M   = (const float*)d_in[i];
    }
    float* out = (float*)d_out;

    const size_t cls_bytes = (size_t)N_CLS * DIM_H * sizeof(uint16_t);  // 4 MB
    if (ws_size >= cls_bytes) {
        uint16_t* cls_bf = (uint16_t*)d_ws;
        scale_cls_kernel<<<(N_CLS * DIM_H) / (256 * 4), 256, 0, stream>>>(cls, M, cls_bf);
        gemm_fused_kernel<<<(N_Q / 128) * (N_CLS / 128), 256, 0, stream>>>(q, cls_bf, out);
    } else {
        naive_kernel<<<(unsigned)(((size_t)N_Q * N_CLS) / 256), 256, 0, stream>>>(q, cls, M, out);
    }
}